// Round 3
// baseline (976.171 us; speedup 1.0000x reference)
//
#include <hip/hip_runtime.h>
#include <hip/hip_cooperative_groups.h>

// Problem constants (from reference)
#define Jd   128   // feature dim
#define Cn   512   // num classes
#define TLn  16    // label seq length
#define Bn   32    // batch
#define RPB  8     // rows per block in precompute

namespace cg = cooperative_groups;

// ---------------------------------------------------------------------------
// Reduction of the reference (x and lens are dead; batch-uniform trajectory):
//   PL[c,tau,:] = label_seqs[c,tau,:] @ W      (precomputed ONCE, 268 MFLOP)
//   pred0       = sos @ W
//   s_0  = argmin_c ||pred0 - L[c,0]||^2 / J
//   s_t  = argmin_c (1/(J*t)) sum_{tau<t} ||PL[s_{t-1},tau] - L[c,tau]||^2
//   out  = [ broadcast_B(s_16) | broadcast_B(PL[s_15]) ]   (f32)
// Sequential dependency handled by ONE cooperative kernel with grid.sync(),
// instead of 17 serial dispatches (round-1's cost was 17 x ~20us of redundant
// per-block L[s]@W recompute + dispatch latency).
// Ties: jnp.argmin takes first index -> packed (simbits<<32 | c) atomicMin
// (sim >= 0 so f32 bit pattern orders like the float).
// ---------------------------------------------------------------------------

// grid = Cn*TLn/RPB + 1 blocks x Jd threads.
// Block g < 1024: PL[g*RPB+i, j] = sum_k L[g*RPB+i, k] * W[k, j]
//   (L row elements are wave-uniform -> scalar loads; W reads coalesced, L2-hot,
//    amortized over RPB rows)
// Last block: pred0 = sos @ W, init argmin keys.
__global__ void k_pre(const float* __restrict__ L,
                      const float* __restrict__ W,
                      const float* __restrict__ sos,
                      float* __restrict__ PL,
                      float* __restrict__ pred0,
                      unsigned long long* __restrict__ key) {
    int j = threadIdx.x;
    int g = blockIdx.x;
    if (g == (Cn * TLn) / RPB) {
        if (j <= TLn) key[j] = 0xFFFFFFFFFFFFFFFFull;
        float acc = 0.f;
        for (int k = 0; k < Jd; ++k)
            acc = fmaf(sos[k], W[k * Jd + j], acc);
        pred0[j] = acc;
        return;
    }
    const float* Lr = L + (size_t)g * RPB * Jd;
    float acc[RPB];
    #pragma unroll
    for (int i = 0; i < RPB; ++i) acc[i] = 0.f;
    for (int k = 0; k < Jd; ++k) {
        float w = W[k * Jd + j];                 // coalesced, L2-resident
        #pragma unroll
        for (int i = 0; i < RPB; ++i)
            acc[i] = fmaf(Lr[i * Jd + k], w, acc[i]);  // uniform -> s_load
    }
    #pragma unroll
    for (int i = 0; i < RPB; ++i)
        PL[((size_t)g * RPB + i) * Jd + j] = acc[i];
}

// Cooperative: grid = Cn blocks x Jd threads (2 blocks/CU -> co-resident).
__global__ void k_loop(const float* __restrict__ L,
                       const float* __restrict__ PL,
                       const float* __restrict__ pred0,
                       unsigned long long* __restrict__ key,
                       float* __restrict__ out) {
    cg::grid_group grid = cg::this_grid();
    int c = blockIdx.x;
    int j = threadIdx.x;
    __shared__ float tmp[2];

    // Hoist this block's L[c] rows into registers: reused by all 17 steps.
    float Lc[TLn];
    #pragma unroll
    for (int tau = 0; tau < TLn; ++tau)
        Lc[tau] = L[((size_t)c * TLn + tau) * Jd + j];

    // ---- t = 0: compare pred0 vs L[c,0] ----
    {
        float d = Lc[0] - pred0[j];
        float partial = d * d;
        for (int o = 32; o > 0; o >>= 1) partial += __shfl_down(partial, o, 64);
        if ((j & 63) == 0) tmp[j >> 6] = partial;
        __syncthreads();
        if (j == 0) {
            float sim = (tmp[0] + tmp[1]) / (float)Jd;
            unsigned long long kk =
                ((unsigned long long)__float_as_uint(sim) << 32) | (unsigned)c;
            atomicMin(&key[0], kk);
        }
        grid.sync();
    }

    // ---- t = 1..16 ----
    for (int t = 1; t <= TLn; ++t) {
        int s = (int)(__hip_atomic_load(&key[t - 1], __ATOMIC_RELAXED,
                                        __HIP_MEMORY_SCOPE_AGENT) & 0xFFFFFFFFull);
        const float* Ps = PL + (size_t)s * TLn * Jd;
        float partial = 0.f;
        #pragma unroll
        for (int tau = 0; tau < TLn; ++tau) {       // fully unrolled: 16 loads in flight
            float d = Lc[tau] - Ps[tau * Jd + j];
            float dd = d * d;
            partial += (tau < t) ? dd : 0.f;        // predicated, always in-bounds
        }
        for (int o = 32; o > 0; o >>= 1) partial += __shfl_down(partial, o, 64);
        if ((j & 63) == 0) tmp[j >> 6] = partial;
        __syncthreads();
        if (j == 0) {
            float sim = (tmp[0] + tmp[1]) / (float)(Jd * t);
            unsigned long long kk =
                ((unsigned long long)__float_as_uint(sim) << 32) | (unsigned)c;
            atomicMin(&key[t], kk);
        }
        grid.sync();
    }

    // ---- output: [sofar(32) | pls(B,TL,J)]; block c covers (b,tau) = (c>>4, c&15)
    int s16 = (int)(__hip_atomic_load(&key[TLn], __ATOMIC_RELAXED,
                                      __HIP_MEMORY_SCOPE_AGENT) & 0xFFFFFFFFull);
    int s15 = (int)(__hip_atomic_load(&key[TLn - 1], __ATOMIC_RELAXED,
                                      __HIP_MEMORY_SCOPE_AGENT) & 0xFFFFFFFFull);
    int tau = c & (TLn - 1);
    out[Bn + (size_t)c * Jd + j] = PL[((size_t)s15 * TLn + tau) * Jd + j];
    if (c == 0 && j < Bn) out[j] = (float)s16;
}

extern "C" void kernel_launch(void* const* d_in, const int* in_sizes, int n_in,
                              void* d_out, int out_size, void* d_ws, size_t ws_size,
                              hipStream_t stream) {
    // inputs: 0:x (dead, f32, 32MB), 1:lens (dead), 2:sos f32, 3:label_seqs f32, 4:W f32
    const float* sos = (const float*)d_in[2];
    const float* L   = (const float*)d_in[3];
    const float* W   = (const float*)d_in[4];
    float* out = (float*)d_out;

    // Scratch layout: key(136B) @0, pred0(512B) @512, PL(4MB) @4096.
    size_t need = 4096 + (size_t)Cn * TLn * Jd * sizeof(float);
    char* base = (ws_size >= need) ? (char*)d_ws : (char*)d_in[0];  // x is a dead input
    unsigned long long* key = (unsigned long long*)base;
    float* pred0 = (float*)(base + 512);
    float* PL    = (float*)(base + 4096);

    hipLaunchKernelGGL(k_pre, dim3((Cn * TLn) / RPB + 1), dim3(Jd), 0, stream,
                       L, W, sos, PL, pred0, key);

    void* args[] = {(void*)&L, (void*)&PL, (void*)&pred0, (void*)&key, (void*)&out};
    hipLaunchCooperativeKernel((void*)k_loop, dim3(Cn), dim3(Jd), args, 0, stream);
}

// Round 4
// 160.294 us; speedup vs baseline: 6.0899x; 6.0899x over previous
//
#include <hip/hip_runtime.h>

// Problem constants
#define Jd   128   // feature dim
#define Cn   512   // num classes
#define TLn  16    // label seq length
#define Bn   32    // batch
#define RPB  8     // rows per block in PL precompute

// ---------------------------------------------------------------------------
// Reduction (x, lens dead; batch-uniform trajectory):
//   PL[c,tau,:] = L[c,tau,:] @ W
//   S0[c]       = ||sos@W - L[c,0]||^2
//   DOT[s,t,c]  = sum_{tau<=t} ||PL[s,tau]-L[c,tau]||^2   (cumulative)
//   s_0 = argmin S0;  s_t = argmin_c DOT[s_{t-1}, t-1, c]
//   out = [ broadcast_B(s_16) | broadcast_B(PL[s_15]) ]
// All heavy work is trajectory-independent -> parallel precompute; the
// sequential chain is 17 argmins over 512 floats in ONE block (no grid.sync:
// round-3 measured ~52us per cooperative grid.sync on 8 XCDs).
// Argmin ties: packed (f32bits<<32 | c) min == jnp first-index semantics.
// ---------------------------------------------------------------------------

// LDS tiles stored TRANSPOSED [j][s] with f4 XOR swizzle: quad q of row j at
// column-quad q^(j&15). Reads: A conflict-free, B 2-way (free). Writes ~8-way
// but write bytes are 16x fewer than read bytes.
#define SWZ(j,q) (((j) << 6) + ((((q) ^ ((j) & 15))) << 2))

// grid = 1024 x 128: PL[g*8+i, j] = sum_k L[g*8+i, k] * W[k, j]
__global__ void k_pre(const float* __restrict__ L, const float* __restrict__ W,
                      float* __restrict__ PL) {
    int j = threadIdx.x, g = blockIdx.x;
    const float* Lr = L + (size_t)g * RPB * Jd;
    float acc[RPB];
    #pragma unroll
    for (int i = 0; i < RPB; ++i) acc[i] = 0.f;
    for (int k = 0; k < Jd; ++k) {
        float w = W[k * Jd + j];                    // coalesced, L2-resident
        #pragma unroll
        for (int i = 0; i < RPB; ++i)
            acc[i] = fmaf(Lr[i * Jd + k], w, acc[i]);   // wave-uniform -> s_load
    }
    #pragma unroll
    for (int i = 0; i < RPB; ++i)
        PL[((size_t)g * RPB + i) * Jd + j] = acc[i];
}

// grid = 1024+4 x 256.
// bid<1024: tau=bid&15, s-tile=(bid>>4)&7, c-tile=bid>>7; computes
//   DOT[s, tau, c] = ||PL[s,tau]-L[c,tau]||^2 for its 64x64 tile.
// bid>=1024: S0 for 128 classes (recomputes pred0 = sos@W locally).
__global__ void k_dot(const float* __restrict__ L, const float* __restrict__ PL,
                      const float* __restrict__ sos, const float* __restrict__ W,
                      float* __restrict__ DOT, float* __restrict__ S0) {
    __shared__ float As[Jd * 64];   // 32 KB
    __shared__ float Bs[Jd * 64];   // 32 KB  (total 64 KB exactly)
    int tid = threadIdx.x, bid = blockIdx.x;

    if (bid >= 1024) {              // ---- S0 path ----
        float* pred0 = As;          // reuse LDS
        if (tid < Jd) {
            float a = 0.f;
            for (int k = 0; k < Jd; ++k) a = fmaf(sos[k], W[k * Jd + tid], a);
            pred0[tid] = a;
        }
        __syncthreads();
        int cb = (bid - 1024) * Jd;              // 128 classes per block
        int w = tid >> 6, lane = tid & 63;
        for (int i = 0; i < 32; ++i) {           // 4 waves x 32 c
            int c = cb + w * 32 + i;
            float d0 = pred0[lane]      - L[(size_t)c * TLn * Jd + lane];
            float d1 = pred0[64 + lane] - L[(size_t)c * TLn * Jd + 64 + lane];
            float p = d0 * d0 + d1 * d1;
            for (int o = 32; o; o >>= 1) p += __shfl_down(p, o, 64);
            if (lane == 0) S0[c] = p;
        }
        return;
    }

    int tau = bid & 15, s0 = ((bid >> 4) & 7) * 64, c0 = (bid >> 7) * 64;
    // Stage 64 PL rows and 64 L rows (plane tau) into swizzled-transposed LDS.
    const float4* A4 = (const float4*)PL;
    const float4* B4 = (const float4*)L;
    #pragma unroll
    for (int q = 0; q < 8; ++q) {
        int idx = q * 256 + tid;                 // 0..2047
        int r = idx >> 5, c4 = idx & 31;         // row 0..63, f4-col 0..31
        int jb = c4 << 2, sq = r >> 2, sl = r & 3;
        float4 va = A4[((size_t)(s0 + r) * TLn + tau) * 32 + c4];
        As[SWZ(jb + 0, sq) + sl] = va.x;
        As[SWZ(jb + 1, sq) + sl] = va.y;
        As[SWZ(jb + 2, sq) + sl] = va.z;
        As[SWZ(jb + 3, sq) + sl] = va.w;
        float4 vb = B4[((size_t)(c0 + r) * TLn + tau) * 32 + c4];
        Bs[SWZ(jb + 0, sq) + sl] = vb.x;
        Bs[SWZ(jb + 1, sq) + sl] = vb.y;
        Bs[SWZ(jb + 2, sq) + sl] = vb.z;
        Bs[SWZ(jb + 3, sq) + sl] = vb.w;
    }
    __syncthreads();

    int sg = tid >> 4, cg = tid & 15;            // 16x16 threads, 4x4 micro
    float acc[4][4];
    #pragma unroll
    for (int i = 0; i < 4; ++i)
        #pragma unroll
        for (int k = 0; k < 4; ++k) acc[i][k] = 0.f;

    #pragma unroll 4
    for (int j = 0; j < Jd; ++j) {
        float4 a4 = *(const float4*)&As[SWZ(j, sg)];
        float4 b4 = *(const float4*)&Bs[SWZ(j, cg)];
        float av[4] = {a4.x, a4.y, a4.z, a4.w};
        float bv[4] = {b4.x, b4.y, b4.z, b4.w};
        #pragma unroll
        for (int i = 0; i < 4; ++i)
            #pragma unroll
            for (int k = 0; k < 4; ++k) {
                float d = av[i] - bv[k];
                acc[i][k] = fmaf(d, d, acc[i][k]);
            }
    }

    float* dst = DOT + (size_t)(s0 + sg * 4) * (TLn * Cn) + tau * Cn + c0 + cg * 4;
    #pragma unroll
    for (int i = 0; i < 4; ++i) {
        float4 v = {acc[i][0], acc[i][1], acc[i][2], acc[i][3]};
        *(float4*)(dst + (size_t)i * (TLn * Cn)) = v;
    }
}

// grid = 1024 x 256: in-place cumsum of DOT over tau for each (s,c). Coalesced.
__global__ void k_cum(float* __restrict__ DOT) {
    int gid = blockIdx.x * 256 + threadIdx.x;    // 0..262143
    int s = gid >> 9, c = gid & 511;
    float* p = DOT + (size_t)s * (TLn * Cn) + c;
    float cum = 0.f;
    #pragma unroll
    for (int t = 0; t < TLn; ++t) { cum += p[(size_t)t * Cn]; p[(size_t)t * Cn] = cum; }
}

__device__ __forceinline__ unsigned long long packkey(float v, int c) {
    return ((unsigned long long)__float_as_uint(v) << 32) | (unsigned int)c;
}

// 1 block x 256: the 17-step argmin chain.
__global__ void k_seq(const float* __restrict__ S0, const float* __restrict__ DOT,
                      int* __restrict__ keys) {
    __shared__ unsigned long long red[4];
    __shared__ int sCur;
    int tid = threadIdx.x, w = tid >> 6, lane = tid & 63;

    for (int t = 0; t <= TLn; ++t) {
        const float* row = (t == 0) ? S0
                         : DOT + (size_t)sCur * (TLn * Cn) + (size_t)(t - 1) * Cn;
        unsigned long long m0 = packkey(row[tid], tid);
        unsigned long long m1 = packkey(row[tid + 256], tid + 256);
        unsigned long long m = (m1 < m0) ? m1 : m0;
        for (int o = 32; o; o >>= 1) {
            unsigned long long o2 = __shfl_down(m, o, 64);
            if (o2 < m) m = o2;
        }
        if (lane == 0) red[w] = m;
        __syncthreads();
        if (tid == 0) {
            unsigned long long b = red[0];
            #pragma unroll
            for (int i = 1; i < 4; ++i) if (red[i] < b) b = red[i];
            int s = (int)(b & 0xFFFFFFFFull);
            sCur = s;
            keys[t] = s;
        }
        __syncthreads();                         // publish sCur for next step
    }
}

// grid = 512 x 128: out = [sofar(32) | pls(B,TL,J)]
__global__ void k_out(const float* __restrict__ PL, const int* __restrict__ keys,
                      float* __restrict__ out) {
    int bt = blockIdx.x, j = threadIdx.x, tau = bt & (TLn - 1);
    int s16 = keys[TLn], s15 = keys[TLn - 1];
    out[Bn + (size_t)bt * Jd + j] = PL[((size_t)s15 * TLn + tau) * Jd + j];
    if (bt == 0 && j < Bn) out[j] = (float)s16;
}

extern "C" void kernel_launch(void* const* d_in, const int* in_sizes, int n_in,
                              void* d_out, int out_size, void* d_ws, size_t ws_size,
                              hipStream_t stream) {
    // inputs: 0:x (dead, 32MB), 1:lens (dead), 2:sos, 3:label_seqs, 4:W  (all f32)
    const float* sos = (const float*)d_in[2];
    const float* L   = (const float*)d_in[3];
    const float* W   = (const float*)d_in[4];
    float* out = (float*)d_out;

    // ws layout: keys(int[32]) @0 | S0(512f) @512 | PL(4MB) @4096 | DOT(16.8MB)
    size_t plOff  = 4096;
    size_t dotOff = plOff + (size_t)Cn * TLn * Jd * sizeof(float);
    size_t need   = dotOff + (size_t)Cn * TLn * Cn * sizeof(float);
    char* base = (ws_size >= need) ? (char*)d_ws : (char*)d_in[0];  // x is dead, 32MB
    int*   keys = (int*)base;
    float* S0   = (float*)(base + 512);
    float* PL   = (float*)(base + plOff);
    float* DOT  = (float*)(base + dotOff);

    hipLaunchKernelGGL(k_pre, dim3(1024), dim3(Jd), 0, stream, L, W, PL);
    hipLaunchKernelGGL(k_dot, dim3(1024 + 4), dim3(256), 0, stream, L, PL, sos, W, DOT, S0);
    hipLaunchKernelGGL(k_cum, dim3(1024), dim3(256), 0, stream, DOT);
    hipLaunchKernelGGL(k_seq, dim3(1), dim3(256), 0, stream, S0, DOT, keys);
    hipLaunchKernelGGL(k_out, dim3(Bn * TLn), dim3(Jd), 0, stream, PL, keys, out);
}